// Round 4
// baseline (421.237 us; speedup 1.0000x reference)
//
#include <hip/hip_runtime.h>
#include <stdint.h>

typedef unsigned long long u64;
typedef unsigned int u32;

#define CONF_T 0.9f
#define IOU_T 0.5f
#define TOPK 4096
#define SORTN 8192

// ---- workspace layout (bytes) ----
#define HIST_OFF     0          // u32[4096]      16384
#define CTR_OFF      16384      // u32[16]: [0]=candCnt [1]=thrB [2]=M
#define BINSTART_OFF 16448      // u32[4096]      16384
#define BINCUR_OFF   32832      // u32[4096]      16384
#define ROWANY_OFF   49216      // u32[4096]      16384
#define SELBOX_OFF   65600      // float4[4096]   65536
#define SELSC_OFF    131136     // float[4096]    16384
#define SELLM_OFF    147520     // float[40960]   163840
#define SORT_OFF     311360     // u64[8192]      65536
#define INTRA_OFF    376896     // u64[4096]      32768
#define MASK_OFF     409664     // u64[4096*64]   2097152
#define CAND_OFF     2506816    // u64[N] worst case ~22 MB (ws is ~420 MiB)

__device__ __forceinline__ int score_bin(float s) {
    u32 b = __float_as_uint(s);
    if (b >= 0x3F800000u) return 0;
    int bin = (int)((0x3F800000u - b) >> 9);
    return bin > 4095 ? 4095 : bin;
}

// K0: zero hist + ctr
__global__ void k_zero(u32* __restrict__ hist, u32* __restrict__ ctr) {
    int i = blockIdx.x * 256 + threadIdx.x;
    hist[i] = 0u;
    if (i < 16) ctr[i] = 0u;
}

// K1: single conf scan: histogram + wave-aggregated candidate compaction
__global__ void k_histcompact(const float4* __restrict__ conf4, int N2,
                              u32* __restrict__ hist, u32* __restrict__ ctr,
                              u64* __restrict__ cand) {
    int stride = gridDim.x * blockDim.x;
    int lane = threadIdx.x & 63;
    for (int i = blockIdx.x * blockDim.x + threadIdx.x; i < N2; i += stride) {
        float4 v = conf4[i];
        bool c0 = v.y > CONF_T, c1 = v.w > CONF_T;
        u64 b0 = __ballot(c0), b1 = __ballot(c1);
        u32 tot = (u32)(__popcll(b0) + __popcll(b1));
        u32 base = 0;
        if (lane == 0 && tot) base = atomicAdd(&ctr[0], tot);
        base = __shfl(base, 0);
        u64 below = ((lane == 63) ? 0xFFFFFFFFFFFFFFFFull : ((1ull << (lane + 1)) - 1ull)) >> 1;
        if (c0) {
            u32 pos = base + (u32)__popcll(b0 & below);
            cand[pos] = ((u64)__float_as_uint(v.y) << 32) | (u64)(~(u32)(2 * i));
            atomicAdd(&hist[score_bin(v.y)], 1u);
        }
        if (c1) {
            u32 pos = base + (u32)__popcll(b0) + (u32)__popcll(b1 & below);
            cand[pos] = ((u64)__float_as_uint(v.w) << 32) | (u64)(~(u32)(2 * i + 1));
            atomicAdd(&hist[score_bin(v.w)], 1u);
        }
    }
}

// K2: full exclusive prefix over 4096 bins + threshold bin B + superset size M
__global__ void __launch_bounds__(256) k_scan(const u32* __restrict__ hist,
                                              u32* __restrict__ binStart,
                                              u32* __restrict__ binCur,
                                              u32* __restrict__ ctr) {
    __shared__ u32 parts[256];
    int t = threadIdx.x;
    u32 h[16];
    u32 sum = 0;
    #pragma unroll
    for (int i = 0; i < 16; i++) { h[i] = hist[t * 16 + i]; sum += h[i]; }
    parts[t] = sum;
    __syncthreads();
    for (int d = 1; d < 256; d <<= 1) {
        u32 add = (t >= d) ? parts[t - d] : 0u;
        __syncthreads();
        parts[t] += add;
        __syncthreads();
    }
    u32 incl = parts[t];
    u32 excl = incl - sum;
    u32 total = parts[255];
    u32 target = total < TOPK ? total : TOPK;
    u32 run = excl;
    #pragma unroll
    for (int i = 0; i < 16; i++) {
        binStart[t * 16 + i] = run;
        binCur[t * 16 + i] = run;
        run += h[i];
    }
    if (total == 0) {
        if (t == 0) { ctr[1] = 0xFFFFFFFFu; ctr[2] = 0u; }
        return;
    }
    if (excl < target && incl >= target) {
        u32 r2 = excl;
        for (int i = 0; i < 16; i++) {
            r2 += h[i];
            if (r2 >= target) { ctr[1] = (u32)(t * 16 + i); ctr[2] = r2; break; }
        }
    }
}

// K3: re-bucket candidates (bin <= B) into per-bin segments (2.2 MB scan, not 22 MB)
__global__ void k_bucket(const u64* __restrict__ cand, const u32* __restrict__ ctr,
                         u32* __restrict__ binCur, u64* __restrict__ sortbuf) {
    u32 C = ctr[0];
    u32 B = ctr[1];
    u32 stride = gridDim.x * blockDim.x;
    for (u32 i = blockIdx.x * blockDim.x + threadIdx.x; i < C; i += stride) {
        u64 key = cand[i];
        float s = __uint_as_float((u32)(key >> 32));
        int bin = score_bin(s);
        if ((u32)bin <= B) {
            u32 pos = atomicAdd(&binCur[bin], 1u);
            if (pos < SORTN) sortbuf[pos] = key;
        }
    }
}

// K4: exact rank within bin + decode + scatter; threads beyond M zero-pad
__global__ void __launch_bounds__(256) k_rankpad(
        const float4* __restrict__ loc, const float4* __restrict__ priors,
        const float* __restrict__ landm, const u64* __restrict__ sortbuf,
        const u32* __restrict__ hist, const u32* __restrict__ binStart,
        const u32* __restrict__ ctr,
        float4* __restrict__ selbox, float* __restrict__ selscore,
        float* __restrict__ sellm) {
    u32 M = ctr[2];
    if (M > SORTN) M = SORTN;
    u32 p = blockIdx.x * 256 + threadIdx.x;
    if (p >= M) {
        if (p < TOPK) {   // zero-pad unused ranks
            selbox[p] = make_float4(0.f, 0.f, 0.f, 0.f);
            selscore[p] = 0.f;
            #pragma unroll
            for (int q = 0; q < 10; q++) sellm[(size_t)p * 10 + q] = 0.f;
        }
        return;
    }
    u64 key = sortbuf[p];
    float sc = __uint_as_float((u32)(key >> 32));
    int bin = score_bin(sc);
    u32 st = binStart[bin];
    u32 cnt = hist[bin];
    u32 end = st + cnt;
    if (end > M) end = M;
    u32 rank = st;
    for (u32 j = st; j < end; j++) {
        rank += (sortbuf[j] > key) ? 1u : 0u;
    }
    if (rank >= TOPK) return;
    u32 idx = ~(u32)key;
    float4 L = loc[idx];
    float4 P = priors[idx];
    float cx = P.x + L.x * 0.1f * P.z;
    float cy = P.y + L.y * 0.1f * P.w;
    float wx = P.z * expf(L.z * 0.2f);
    float wy = P.w * expf(L.w * 0.2f);
    float4 bx;
    bx.x = (cx - 0.5f * wx) * 8192.f;
    bx.y = (cy - 0.5f * wy) * 8192.f;
    bx.z = (cx + 0.5f * wx) * 8192.f;
    bx.w = (cy + 0.5f * wy) * 8192.f;
    selbox[rank] = bx;
    selscore[rank] = sc;
    const float* lmr = landm + (size_t)idx * 10;
    float* lmo = sellm + (size_t)rank * 10;
    #pragma unroll
    for (int q = 0; q < 5; q++) {
        float lx = lmr[2 * q], ly = lmr[2 * q + 1];
        lmo[2 * q]     = (P.x + lx * 0.1f * P.z) * 8192.f;
        lmo[2 * q + 1] = (P.y + ly * 0.1f * P.w) * 8192.f;
    }
}

// K5: mask matrix, conflict-free. Wave handles 4 rows; for word w lanes read
// consecutive sb[w*64+lane] (no bank conflicts), ballot forms the word, lane w
// keeps it; final row store is one coalesced 64-lane store.
__global__ void __launch_bounds__(256) k_mask(const float4* __restrict__ selbox,
                                              u64* __restrict__ mask,
                                              u32* __restrict__ rowAny,
                                              u64* __restrict__ intraBuf) {
    __shared__ float4 sb[TOPK];   // 64 KB
    int t = threadIdx.x, b = blockIdx.x;
    for (int i = t; i < TOPK; i += 256) sb[i] = selbox[i];
    __syncthreads();
    int wv = t >> 6, lane = t & 63;
    int rbase = b * 16 + wv * 4;
    float4 r0 = sb[rbase], r1 = sb[rbase + 1], r2 = sb[rbase + 2], r3 = sb[rbase + 3];
    float a0 = fmaxf(r0.z - r0.x, 0.f) * fmaxf(r0.w - r0.y, 0.f);
    float a1 = fmaxf(r1.z - r1.x, 0.f) * fmaxf(r1.w - r1.y, 0.f);
    float a2 = fmaxf(r2.z - r2.x, 0.f) * fmaxf(r2.w - r2.y, 0.f);
    float a3 = fmaxf(r3.z - r3.x, 0.f) * fmaxf(r3.w - r3.y, 0.f);
    u64 w0 = 0, w1 = 0, w2 = 0, w3 = 0;
    for (int w = 0; w < 64; w++) {
        if (w * 64 + 63 <= rbase) continue;   // whole word below all 4 rows
        int j = w * 64 + lane;
        float4 bj = sb[j];
        float aj = fmaxf(bj.z - bj.x, 0.f) * fmaxf(bj.w - bj.y, 0.f);
        #define IOU_BIT(rr, aa, row) ({ \
            float lx = fmaxf(rr.x, bj.x), ly = fmaxf(rr.y, bj.y); \
            float rx = fminf(rr.z, bj.z), ry = fminf(rr.w, bj.w); \
            float inter = fmaxf(rx - lx, 0.f) * fmaxf(ry - ly, 0.f); \
            float iou = inter / (aa + aj - inter + 1e-12f); \
            (j > (row)) && (iou > IOU_T); })
        u64 bb0 = __ballot(IOU_BIT(r0, a0, rbase + 0));
        u64 bb1 = __ballot(IOU_BIT(r1, a1, rbase + 1));
        u64 bb2 = __ballot(IOU_BIT(r2, a2, rbase + 2));
        u64 bb3 = __ballot(IOU_BIT(r3, a3, rbase + 3));
        #undef IOU_BIT
        if (lane == w) { w0 = bb0; w1 = bb1; w2 = bb2; w3 = bb3; }
    }
    mask[(size_t)(rbase + 0) * 64 + lane] = w0;
    mask[(size_t)(rbase + 1) * 64 + lane] = w1;
    mask[(size_t)(rbase + 2) * 64 + lane] = w2;
    mask[(size_t)(rbase + 3) * 64 + lane] = w3;
    u64 nz0 = __ballot(w0 != 0ull), nz1 = __ballot(w1 != 0ull);
    u64 nz2 = __ballot(w2 != 0ull), nz3 = __ballot(w3 != 0ull);
    if (lane == 0) {
        rowAny[rbase + 0] = nz0 ? 1u : 0u;
        rowAny[rbase + 1] = nz1 ? 1u : 0u;
        rowAny[rbase + 2] = nz2 ? 1u : 0u;
        rowAny[rbase + 3] = nz3 ? 1u : 0u;
    }
    if (lane == ((rbase + 0) >> 6)) intraBuf[rbase + 0] = w0;
    if (lane == ((rbase + 1) >> 6)) intraBuf[rbase + 1] = w1;
    if (lane == ((rbase + 2) >> 6)) intraBuf[rbase + 2] = w2;
    if (lane == ((rbase + 3) >> 6)) intraBuf[rbase + 3] = w3;
}

// K6: fused ballots + serial greedy NMS (batched suppressor loads) + output write
__global__ void __launch_bounds__(256) k_nms(const u64* __restrict__ mask,
                                             const float* __restrict__ selscore,
                                             const u32* __restrict__ rowAny,
                                             const u64* __restrict__ intraBuf,
                                             const float4* __restrict__ selbox,
                                             const float* __restrict__ sellm,
                                             float* __restrict__ out) {
    __shared__ u64 intra_s[4096];   // 32 KB
    __shared__ u64 validw_s[64], nzw_s[64], keep_s[64];
    int tid = threadIdx.x;
    int wv = tid >> 6, lane = tid & 63;
    for (int i = tid; i < 4096; i += 256) intra_s[i] = intraBuf[i];
    for (int g = wv; g < 64; g += 4) {
        float s = selscore[g * 64 + lane];
        u32 ra = rowAny[g * 64 + lane];
        u64 vb = __ballot(s > CONF_T);
        u64 nb = __ballot(ra != 0u);
        if (lane == 0) { validw_s[g] = vb; nzw_s[g] = nb; }
    }
    __syncthreads();
    if (wv == 0) {
        int t = lane;
        u64 vw = validw_s[t];
        u64 nzv = nzw_s[t];
        u64 sup = 0ull, keepw = 0ull;
        for (int g = 0; g < 64; g++) {
            u64 cur = __shfl(sup, g);
            u64 validg = __shfl(vw, g);
            u64 nzg = __shfl(nzv, g);
            u64 alive = (~cur) & validg;
            if (nzg) {
                u64 intra = intra_s[g * 64 + t];
                u64 rem = nzg;
                while (rem) {
                    int bb = __ffsll((long long)rem) - 1;
                    rem &= rem - 1;
                    if ((alive >> bb) & 1ull) {
                        u64 rowb = __shfl(intra, bb);
                        alive &= ~rowb;
                    }
                }
            }
            if (t == g) keepw = alive;
            // batched suppressor-row loads (independent -> overlap latency 8x)
            u64 srem = alive & nzg;
            const u64* mb = mask + (size_t)(g * 64) * 64 + t;
            while (srem) {
                int i0, i1 = -1, i2 = -1, i3 = -1, i4 = -1, i5 = -1, i6 = -1, i7 = -1;
                i0 = __ffsll((long long)srem) - 1; srem &= srem - 1;
                if (srem) { i1 = __ffsll((long long)srem) - 1; srem &= srem - 1;
                if (srem) { i2 = __ffsll((long long)srem) - 1; srem &= srem - 1;
                if (srem) { i3 = __ffsll((long long)srem) - 1; srem &= srem - 1;
                if (srem) { i4 = __ffsll((long long)srem) - 1; srem &= srem - 1;
                if (srem) { i5 = __ffsll((long long)srem) - 1; srem &= srem - 1;
                if (srem) { i6 = __ffsll((long long)srem) - 1; srem &= srem - 1;
                if (srem) { i7 = __ffsll((long long)srem) - 1; srem &= srem - 1; } } } } } } }
                u64 a0 = mb[(size_t)i0 * 64];
                u64 a1 = (i1 >= 0) ? mb[(size_t)i1 * 64] : 0ull;
                u64 a2 = (i2 >= 0) ? mb[(size_t)i2 * 64] : 0ull;
                u64 a3 = (i3 >= 0) ? mb[(size_t)i3 * 64] : 0ull;
                u64 a4 = (i4 >= 0) ? mb[(size_t)i4 * 64] : 0ull;
                u64 a5 = (i5 >= 0) ? mb[(size_t)i5 * 64] : 0ull;
                u64 a6 = (i6 >= 0) ? mb[(size_t)i6 * 64] : 0ull;
                u64 a7 = (i7 >= 0) ? mb[(size_t)i7 * 64] : 0ull;
                sup |= (a0 | a1) | (a2 | a3) | ((a4 | a5) | (a6 | a7));
            }
        }
        keep_s[t] = keepw;
    }
    __syncthreads();
    // coalesced output write: out[f], f = row*15 + col
    const float* sbf = (const float*)selbox;
    for (int f = tid; f < TOPK * 15; f += 256) {
        int row = f / 15;
        int col = f - row * 15;
        bool kp = (keep_s[row >> 6] >> (row & 63)) & 1ull;
        float val;
        if (col < 4)       val = sbf[row * 4 + col];
        else if (col == 4) val = selscore[row];
        else               val = sellm[(size_t)row * 10 + (col - 5)];
        out[f] = kp ? val : 0.f;
    }
}

extern "C" void kernel_launch(void* const* d_in, const int* in_sizes, int n_in,
                              void* d_out, int out_size, void* d_ws, size_t ws_size,
                              hipStream_t stream) {
    const float4* loc    = (const float4*)d_in[0];
    const float4* conf4  = (const float4*)d_in[1];
    const float*  landm  = (const float*)d_in[2];
    const float4* priors = (const float4*)d_in[3];
    float* out = (float*)d_out;
    int N = in_sizes[1] / 2;
    int N2 = N / 2;   // float4 elements (2 anchors each); N is even here

    char* ws = (char*)d_ws;
    u32* hist     = (u32*)(ws + HIST_OFF);
    u32* ctr      = (u32*)(ws + CTR_OFF);
    u32* binStart = (u32*)(ws + BINSTART_OFF);
    u32* binCur   = (u32*)(ws + BINCUR_OFF);
    u32* rowAny   = (u32*)(ws + ROWANY_OFF);
    float4* selbox = (float4*)(ws + SELBOX_OFF);
    float* selsc   = (float*)(ws + SELSC_OFF);
    float* sellm   = (float*)(ws + SELLM_OFF);
    u64* sortbuf  = (u64*)(ws + SORT_OFF);
    u64* intraBuf = (u64*)(ws + INTRA_OFF);
    u64* maskp    = (u64*)(ws + MASK_OFF);
    u64* cand     = (u64*)(ws + CAND_OFF);

    k_zero<<<16, 256, 0, stream>>>(hist, ctr);
    k_histcompact<<<2048, 256, 0, stream>>>(conf4, N2, hist, ctr, cand);
    k_scan<<<1, 256, 0, stream>>>(hist, binStart, binCur, ctr);
    k_bucket<<<128, 256, 0, stream>>>(cand, ctr, binCur, sortbuf);
    k_rankpad<<<32, 256, 0, stream>>>(loc, priors, landm, sortbuf, hist, binStart, ctr,
                                      selbox, selsc, sellm);
    k_mask<<<256, 256, 0, stream>>>(selbox, maskp, rowAny, intraBuf);
    k_nms<<<1, 256, 0, stream>>>(maskp, selsc, rowAny, intraBuf, selbox, sellm, out);
}

// Round 5
// 200.589 us; speedup vs baseline: 2.1000x; 2.1000x over previous
//
#include <hip/hip_runtime.h>
#include <stdint.h>

typedef unsigned long long u64;
typedef unsigned int u32;

#define CONF_T 0.9f
#define IOU_T 0.5f
#define TOPK 4096
#define SORTN 8192

// ---- workspace layout (bytes) ----
#define HIST_OFF     0          // u32[4096]      16384
#define CTR_OFF      16384      // u32[16]: [1]=thrB [2]=M
#define BINSTART_OFF 16448      // u32[4096]      16384
#define BINCUR_OFF   32832      // u32[4096]      16384
#define ROWANY_OFF   49216      // u32[4096]      16384
#define SELBOX_OFF   65600      // float4[4096]   65536
#define SELSC_OFF    131136     // float[4096]    16384
#define SELLM_OFF    147520     // float[40960]   163840
#define SORT_OFF     311360     // u64[8192]      65536
#define INTRA_OFF    376896     // u64[4096]      32768
#define CNT_OFF      409664     // u32[2048]      8192
#define MASK_OFF     417856     // u64[4096*64]   2097152
#define CAND_OFF     2515008    // u64 block segments, ~22 MB worst case

__device__ __forceinline__ int score_bin(float s) {
    u32 b = __float_as_uint(s);
    if (b >= 0x3F800000u) return 0;
    int bin = (int)((0x3F800000u - b) >> 9);
    return bin > 4095 ? 4095 : bin;
}

// K0: zero hist + ctr
__global__ void k_zero(u32* __restrict__ hist, u32* __restrict__ ctr) {
    int i = blockIdx.x * 256 + threadIdx.x;
    hist[i] = 0u;
    if (i < 16) ctr[i] = 0u;
}

// K1: single conf scan: histogram + block-segmented candidate compaction.
// No global counter: each block owns cand[b*segStride .. ] with an LDS counter.
__global__ void __launch_bounds__(256) k_histcompact(
        const float4* __restrict__ conf4, int N2, int chunk,
        u32* __restrict__ hist, u32* __restrict__ cnt, u64* __restrict__ cand) {
    __shared__ u32 lcnt;
    int tid = threadIdx.x, b = blockIdx.x;
    if (tid == 0) lcnt = 0u;
    __syncthreads();
    int start = b * chunk;
    int end = start + chunk;
    if (end > N2) end = N2;
    u64* seg = cand + (size_t)b * (size_t)(chunk * 2);
    for (int i = start + tid; i < end; i += 256) {
        float4 v = conf4[i];
        if (v.y > CONF_T) {
            atomicAdd(&hist[score_bin(v.y)], 1u);
            u32 pos = atomicAdd(&lcnt, 1u);
            seg[pos] = ((u64)__float_as_uint(v.y) << 32) | (u64)(~(u32)(2 * i));
        }
        if (v.w > CONF_T) {
            atomicAdd(&hist[score_bin(v.w)], 1u);
            u32 pos = atomicAdd(&lcnt, 1u);
            seg[pos] = ((u64)__float_as_uint(v.w) << 32) | (u64)(~(u32)(2 * i + 1));
        }
    }
    __syncthreads();
    if (tid == 0) cnt[b] = lcnt;
}

// K2: full exclusive prefix over 4096 bins + threshold bin B + superset size M
__global__ void __launch_bounds__(256) k_scan(const u32* __restrict__ hist,
                                              u32* __restrict__ binStart,
                                              u32* __restrict__ binCur,
                                              u32* __restrict__ ctr) {
    __shared__ u32 parts[256];
    int t = threadIdx.x;
    u32 h[16];
    u32 sum = 0;
    #pragma unroll
    for (int i = 0; i < 16; i++) { h[i] = hist[t * 16 + i]; sum += h[i]; }
    parts[t] = sum;
    __syncthreads();
    for (int d = 1; d < 256; d <<= 1) {
        u32 add = (t >= d) ? parts[t - d] : 0u;
        __syncthreads();
        parts[t] += add;
        __syncthreads();
    }
    u32 incl = parts[t];
    u32 excl = incl - sum;
    u32 total = parts[255];
    u32 target = total < TOPK ? total : TOPK;
    u32 run = excl;
    #pragma unroll
    for (int i = 0; i < 16; i++) {
        binStart[t * 16 + i] = run;
        binCur[t * 16 + i] = run;
        run += h[i];
    }
    if (total == 0) {
        if (t == 0) { ctr[1] = 0xFFFFFFFFu; ctr[2] = 0u; }
        return;
    }
    if (excl < target && incl >= target) {
        u32 r2 = excl;
        for (int i = 0; i < 16; i++) {
            r2 += h[i];
            if (r2 >= target) { ctr[1] = (u32)(t * 16 + i); ctr[2] = r2; break; }
        }
    }
}

// K3: re-bucket candidates (bin <= B) from block segments into per-bin segments
__global__ void k_bucket(const u64* __restrict__ cand, const u32* __restrict__ cnt,
                         int chunk, const u32* __restrict__ ctr,
                         u32* __restrict__ binCur, u64* __restrict__ sortbuf) {
    int b = blockIdx.x;
    u32 n = cnt[b];
    u32 B = ctr[1];
    const u64* seg = cand + (size_t)b * (size_t)(chunk * 2);
    for (u32 i = threadIdx.x; i < n; i += 64) {
        u64 key = seg[i];
        float s = __uint_as_float((u32)(key >> 32));
        int bin = score_bin(s);
        if ((u32)bin <= B) {
            u32 pos = atomicAdd(&binCur[bin], 1u);
            if (pos < SORTN) sortbuf[pos] = key;
        }
    }
}

// K4: exact rank within bin + decode + scatter; threads beyond M zero-pad
__global__ void __launch_bounds__(256) k_rankpad(
        const float4* __restrict__ loc, const float4* __restrict__ priors,
        const float* __restrict__ landm, const u64* __restrict__ sortbuf,
        const u32* __restrict__ hist, const u32* __restrict__ binStart,
        const u32* __restrict__ ctr,
        float4* __restrict__ selbox, float* __restrict__ selscore,
        float* __restrict__ sellm) {
    u32 M = ctr[2];
    if (M > SORTN) M = SORTN;
    u32 p = blockIdx.x * 256 + threadIdx.x;
    if (p >= M) {
        if (p < TOPK) {
            selbox[p] = make_float4(0.f, 0.f, 0.f, 0.f);
            selscore[p] = 0.f;
            #pragma unroll
            for (int q = 0; q < 10; q++) sellm[(size_t)p * 10 + q] = 0.f;
        }
        return;
    }
    u64 key = sortbuf[p];
    float sc = __uint_as_float((u32)(key >> 32));
    int bin = score_bin(sc);
    u32 st = binStart[bin];
    u32 cnt = hist[bin];
    u32 end = st + cnt;
    if (end > M) end = M;
    u32 rank = st;
    for (u32 j = st; j < end; j++) {
        rank += (sortbuf[j] > key) ? 1u : 0u;
    }
    if (rank >= TOPK) return;
    u32 idx = ~(u32)key;
    float4 L = loc[idx];
    float4 P = priors[idx];
    float cx = P.x + L.x * 0.1f * P.z;
    float cy = P.y + L.y * 0.1f * P.w;
    float wx = P.z * expf(L.z * 0.2f);
    float wy = P.w * expf(L.w * 0.2f);
    float4 bx;
    bx.x = (cx - 0.5f * wx) * 8192.f;
    bx.y = (cy - 0.5f * wy) * 8192.f;
    bx.z = (cx + 0.5f * wx) * 8192.f;
    bx.w = (cy + 0.5f * wy) * 8192.f;
    selbox[rank] = bx;
    selscore[rank] = sc;
    const float* lmr = landm + (size_t)idx * 10;
    float* lmo = sellm + (size_t)rank * 10;
    #pragma unroll
    for (int q = 0; q < 5; q++) {
        float lx = lmr[2 * q], ly = lmr[2 * q + 1];
        lmo[2 * q]     = (P.x + lx * 0.1f * P.z) * 8192.f;
        lmo[2 * q + 1] = (P.y + ly * 0.1f * P.w) * 8192.f;
    }
}

// K5: mask matrix, conflict-free. Wave handles 4 rows; for word w lanes read
// consecutive sb[w*64+lane] (no bank conflicts), ballot forms the word, lane w
// keeps it; final row store is one coalesced 64-lane store.
__global__ void __launch_bounds__(256) k_mask(const float4* __restrict__ selbox,
                                              u64* __restrict__ mask,
                                              u32* __restrict__ rowAny,
                                              u64* __restrict__ intraBuf) {
    __shared__ float4 sb[TOPK];   // 64 KB
    int t = threadIdx.x, b = blockIdx.x;
    for (int i = t; i < TOPK; i += 256) sb[i] = selbox[i];
    __syncthreads();
    int wv = t >> 6, lane = t & 63;
    int rbase = b * 16 + wv * 4;
    float4 r0 = sb[rbase], r1 = sb[rbase + 1], r2 = sb[rbase + 2], r3 = sb[rbase + 3];
    float a0 = fmaxf(r0.z - r0.x, 0.f) * fmaxf(r0.w - r0.y, 0.f);
    float a1 = fmaxf(r1.z - r1.x, 0.f) * fmaxf(r1.w - r1.y, 0.f);
    float a2 = fmaxf(r2.z - r2.x, 0.f) * fmaxf(r2.w - r2.y, 0.f);
    float a3 = fmaxf(r3.z - r3.x, 0.f) * fmaxf(r3.w - r3.y, 0.f);
    u64 w0 = 0, w1 = 0, w2 = 0, w3 = 0;
    for (int w = 0; w < 64; w++) {
        if (w * 64 + 63 <= rbase) continue;
        int j = w * 64 + lane;
        float4 bj = sb[j];
        float aj = fmaxf(bj.z - bj.x, 0.f) * fmaxf(bj.w - bj.y, 0.f);
        #define IOU_BIT(rr, aa, row) ({ \
            float lx = fmaxf(rr.x, bj.x), ly = fmaxf(rr.y, bj.y); \
            float rx = fminf(rr.z, bj.z), ry = fminf(rr.w, bj.w); \
            float inter = fmaxf(rx - lx, 0.f) * fmaxf(ry - ly, 0.f); \
            float iou = inter / (aa + aj - inter + 1e-12f); \
            (j > (row)) && (iou > IOU_T); })
        u64 bb0 = __ballot(IOU_BIT(r0, a0, rbase + 0));
        u64 bb1 = __ballot(IOU_BIT(r1, a1, rbase + 1));
        u64 bb2 = __ballot(IOU_BIT(r2, a2, rbase + 2));
        u64 bb3 = __ballot(IOU_BIT(r3, a3, rbase + 3));
        #undef IOU_BIT
        if (lane == w) { w0 = bb0; w1 = bb1; w2 = bb2; w3 = bb3; }
    }
    mask[(size_t)(rbase + 0) * 64 + lane] = w0;
    mask[(size_t)(rbase + 1) * 64 + lane] = w1;
    mask[(size_t)(rbase + 2) * 64 + lane] = w2;
    mask[(size_t)(rbase + 3) * 64 + lane] = w3;
    u64 nz0 = __ballot(w0 != 0ull), nz1 = __ballot(w1 != 0ull);
    u64 nz2 = __ballot(w2 != 0ull), nz3 = __ballot(w3 != 0ull);
    if (lane == 0) {
        rowAny[rbase + 0] = nz0 ? 1u : 0u;
        rowAny[rbase + 1] = nz1 ? 1u : 0u;
        rowAny[rbase + 2] = nz2 ? 1u : 0u;
        rowAny[rbase + 3] = nz3 ? 1u : 0u;
    }
    if (lane == ((rbase + 0) >> 6)) intraBuf[rbase + 0] = w0;
    if (lane == ((rbase + 1) >> 6)) intraBuf[rbase + 1] = w1;
    if (lane == ((rbase + 2) >> 6)) intraBuf[rbase + 2] = w2;
    if (lane == ((rbase + 3) >> 6)) intraBuf[rbase + 3] = w3;
}

// K6: fused ballots + serial greedy NMS (batched suppressor loads) + output write
__global__ void __launch_bounds__(256) k_nms(const u64* __restrict__ mask,
                                             const float* __restrict__ selscore,
                                             const u32* __restrict__ rowAny,
                                             const u64* __restrict__ intraBuf,
                                             const float4* __restrict__ selbox,
                                             const float* __restrict__ sellm,
                                             float* __restrict__ out) {
    __shared__ u64 intra_s[4096];   // 32 KB
    __shared__ u64 validw_s[64], nzw_s[64], keep_s[64];
    int tid = threadIdx.x;
    int wv = tid >> 6, lane = tid & 63;
    for (int i = tid; i < 4096; i += 256) intra_s[i] = intraBuf[i];
    for (int g = wv; g < 64; g += 4) {
        float s = selscore[g * 64 + lane];
        u32 ra = rowAny[g * 64 + lane];
        u64 vb = __ballot(s > CONF_T);
        u64 nb = __ballot(ra != 0u);
        if (lane == 0) { validw_s[g] = vb; nzw_s[g] = nb; }
    }
    __syncthreads();
    if (wv == 0) {
        int t = lane;
        u64 vw = validw_s[t];
        u64 nzv = nzw_s[t];
        u64 sup = 0ull, keepw = 0ull;
        for (int g = 0; g < 64; g++) {
            u64 cur = __shfl(sup, g);
            u64 validg = __shfl(vw, g);
            u64 nzg = __shfl(nzv, g);
            u64 alive = (~cur) & validg;
            if (nzg) {
                u64 intra = intra_s[g * 64 + t];
                u64 rem = nzg;
                while (rem) {
                    int bb = __ffsll((long long)rem) - 1;
                    rem &= rem - 1;
                    if ((alive >> bb) & 1ull) {
                        u64 rowb = __shfl(intra, bb);
                        alive &= ~rowb;
                    }
                }
            }
            if (t == g) keepw = alive;
            u64 srem = alive & nzg;
            const u64* mb = mask + (size_t)(g * 64) * 64 + t;
            while (srem) {
                int i0, i1 = -1, i2 = -1, i3 = -1, i4 = -1, i5 = -1, i6 = -1, i7 = -1;
                i0 = __ffsll((long long)srem) - 1; srem &= srem - 1;
                if (srem) { i1 = __ffsll((long long)srem) - 1; srem &= srem - 1;
                if (srem) { i2 = __ffsll((long long)srem) - 1; srem &= srem - 1;
                if (srem) { i3 = __ffsll((long long)srem) - 1; srem &= srem - 1;
                if (srem) { i4 = __ffsll((long long)srem) - 1; srem &= srem - 1;
                if (srem) { i5 = __ffsll((long long)srem) - 1; srem &= srem - 1;
                if (srem) { i6 = __ffsll((long long)srem) - 1; srem &= srem - 1;
                if (srem) { i7 = __ffsll((long long)srem) - 1; srem &= srem - 1; } } } } } } }
                u64 a0 = mb[(size_t)i0 * 64];
                u64 a1 = (i1 >= 0) ? mb[(size_t)i1 * 64] : 0ull;
                u64 a2 = (i2 >= 0) ? mb[(size_t)i2 * 64] : 0ull;
                u64 a3 = (i3 >= 0) ? mb[(size_t)i3 * 64] : 0ull;
                u64 a4 = (i4 >= 0) ? mb[(size_t)i4 * 64] : 0ull;
                u64 a5 = (i5 >= 0) ? mb[(size_t)i5 * 64] : 0ull;
                u64 a6 = (i6 >= 0) ? mb[(size_t)i6 * 64] : 0ull;
                u64 a7 = (i7 >= 0) ? mb[(size_t)i7 * 64] : 0ull;
                sup |= (a0 | a1) | (a2 | a3) | ((a4 | a5) | (a6 | a7));
            }
        }
        keep_s[t] = keepw;
    }
    __syncthreads();
    const float* sbf = (const float*)selbox;
    for (int f = tid; f < TOPK * 15; f += 256) {
        int row = f / 15;
        int col = f - row * 15;
        bool kp = (keep_s[row >> 6] >> (row & 63)) & 1ull;
        float val;
        if (col < 4)       val = sbf[row * 4 + col];
        else if (col == 4) val = selscore[row];
        else               val = sellm[(size_t)row * 10 + (col - 5)];
        out[f] = kp ? val : 0.f;
    }
}

extern "C" void kernel_launch(void* const* d_in, const int* in_sizes, int n_in,
                              void* d_out, int out_size, void* d_ws, size_t ws_size,
                              hipStream_t stream) {
    const float4* loc    = (const float4*)d_in[0];
    const float4* conf4  = (const float4*)d_in[1];
    const float*  landm  = (const float*)d_in[2];
    const float4* priors = (const float4*)d_in[3];
    float* out = (float*)d_out;
    int N = in_sizes[1] / 2;
    int N2 = N / 2;   // float4 elements (2 anchors each)
    const int NBLK = 2048;
    int chunk = (N2 + NBLK - 1) / NBLK;   // float4s per block segment

    char* ws = (char*)d_ws;
    u32* hist     = (u32*)(ws + HIST_OFF);
    u32* ctr      = (u32*)(ws + CTR_OFF);
    u32* binStart = (u32*)(ws + BINSTART_OFF);
    u32* binCur   = (u32*)(ws + BINCUR_OFF);
    u32* rowAny   = (u32*)(ws + ROWANY_OFF);
    float4* selbox = (float4*)(ws + SELBOX_OFF);
    float* selsc   = (float*)(ws + SELSC_OFF);
    float* sellm   = (float*)(ws + SELLM_OFF);
    u64* sortbuf  = (u64*)(ws + SORT_OFF);
    u64* intraBuf = (u64*)(ws + INTRA_OFF);
    u32* cnt      = (u32*)(ws + CNT_OFF);
    u64* maskp    = (u64*)(ws + MASK_OFF);
    u64* cand     = (u64*)(ws + CAND_OFF);

    k_zero<<<16, 256, 0, stream>>>(hist, ctr);
    k_histcompact<<<NBLK, 256, 0, stream>>>(conf4, N2, chunk, hist, cnt, cand);
    k_scan<<<1, 256, 0, stream>>>(hist, binStart, binCur, ctr);
    k_bucket<<<NBLK, 64, 0, stream>>>(cand, cnt, chunk, ctr, binCur, sortbuf);
    k_rankpad<<<32, 256, 0, stream>>>(loc, priors, landm, sortbuf, hist, binStart, ctr,
                                      selbox, selsc, sellm);
    k_mask<<<256, 256, 0, stream>>>(selbox, maskp, rowAny, intraBuf);
    k_nms<<<1, 256, 0, stream>>>(maskp, selsc, rowAny, intraBuf, selbox, sellm, out);
}

// Round 6
// 120.120 us; speedup vs baseline: 3.5068x; 1.6699x over previous
//
#include <hip/hip_runtime.h>
#include <stdint.h>

typedef unsigned long long u64;
typedef unsigned int u32;

#define CONF_T 0.9f
#define IOU_T 0.5f
#define TOPK 4096
#define SORTN 8192

// ---- workspace layout (bytes) ----
#define HIST_OFF     0          // u32[4096]      16384
#define CTR_OFF      16384      // u32[16]: [1]=thrB [2]=M
#define BINSTART_OFF 16448      // u32[4096]      16384
#define BINCUR_OFF   32832      // u32[4096]      16384
#define VALIDW_OFF   49216      // u64[64]        512
#define NZW_OFF      49728      // u64[64]        512
#define KEEP_OFF     50240      // u64[64]        512
#define SELBOX_OFF   65600      // float4[4096]   65536
#define SELSC_OFF    131136     // float[4096]    16384
#define SELLM_OFF    147520     // float[40960]   163840
#define SORT_OFF     311360     // u64[8192]      65536
#define CNT_OFF      376896     // u32[2048]      8192
#define MASK_OFF     385088     // u64[4096*64]   2097152
#define CAND_OFF     2482240    // u64 block segments, ~22 MB worst case

__device__ __forceinline__ int score_bin(float s) {
    u32 b = __float_as_uint(s);
    if (b >= 0x3F800000u) return 0;
    int bin = (int)((0x3F800000u - b) >> 9);
    return bin > 4095 ? 4095 : bin;
}

// K0: zero hist + ctr + validw/nzw
__global__ void k_zero(u32* __restrict__ hist, u32* __restrict__ ctr,
                       u64* __restrict__ validw, u64* __restrict__ nzw) {
    int i = blockIdx.x * 256 + threadIdx.x;
    hist[i] = 0u;
    if (i < 16) ctr[i] = 0u;
    if (i < 64) { validw[i] = 0ull; nzw[i] = 0ull; }
}

// K1: single conf scan: histogram + block-segmented candidate compaction.
__global__ void __launch_bounds__(256) k_histcompact(
        const float4* __restrict__ conf4, int N2, int chunk,
        u32* __restrict__ hist, u32* __restrict__ cnt, u64* __restrict__ cand) {
    __shared__ u32 lcnt;
    int tid = threadIdx.x, b = blockIdx.x;
    if (tid == 0) lcnt = 0u;
    __syncthreads();
    int start = b * chunk;
    int end = start + chunk;
    if (end > N2) end = N2;
    u64* seg = cand + (size_t)b * (size_t)(chunk * 2);
    for (int i = start + tid; i < end; i += 256) {
        float4 v = conf4[i];
        if (v.y > CONF_T) {
            atomicAdd(&hist[score_bin(v.y)], 1u);
            u32 pos = atomicAdd(&lcnt, 1u);
            seg[pos] = ((u64)__float_as_uint(v.y) << 32) | (u64)(~(u32)(2 * i));
        }
        if (v.w > CONF_T) {
            atomicAdd(&hist[score_bin(v.w)], 1u);
            u32 pos = atomicAdd(&lcnt, 1u);
            seg[pos] = ((u64)__float_as_uint(v.w) << 32) | (u64)(~(u32)(2 * i + 1));
        }
    }
    __syncthreads();
    if (tid == 0) cnt[b] = lcnt;
}

// K2: full exclusive prefix over 4096 bins + threshold bin B + superset size M
__global__ void __launch_bounds__(256) k_scan(const u32* __restrict__ hist,
                                              u32* __restrict__ binStart,
                                              u32* __restrict__ binCur,
                                              u32* __restrict__ ctr) {
    __shared__ u32 parts[256];
    int t = threadIdx.x;
    u32 h[16];
    u32 sum = 0;
    #pragma unroll
    for (int i = 0; i < 16; i++) { h[i] = hist[t * 16 + i]; sum += h[i]; }
    parts[t] = sum;
    __syncthreads();
    for (int d = 1; d < 256; d <<= 1) {
        u32 add = (t >= d) ? parts[t - d] : 0u;
        __syncthreads();
        parts[t] += add;
        __syncthreads();
    }
    u32 incl = parts[t];
    u32 excl = incl - sum;
    u32 total = parts[255];
    u32 target = total < TOPK ? total : TOPK;
    u32 run = excl;
    #pragma unroll
    for (int i = 0; i < 16; i++) {
        binStart[t * 16 + i] = run;
        binCur[t * 16 + i] = run;
        run += h[i];
    }
    if (total == 0) {
        if (t == 0) { ctr[1] = 0xFFFFFFFFu; ctr[2] = 0u; }
        return;
    }
    if (excl < target && incl >= target) {
        u32 r2 = excl;
        for (int i = 0; i < 16; i++) {
            r2 += h[i];
            if (r2 >= target) { ctr[1] = (u32)(t * 16 + i); ctr[2] = r2; break; }
        }
    }
}

// K3: re-bucket candidates (bin <= B) from block segments into per-bin segments
__global__ void k_bucket(const u64* __restrict__ cand, const u32* __restrict__ cnt,
                         int chunk, const u32* __restrict__ ctr,
                         u32* __restrict__ binCur, u64* __restrict__ sortbuf) {
    int b = blockIdx.x;
    u32 n = cnt[b];
    u32 B = ctr[1];
    const u64* seg = cand + (size_t)b * (size_t)(chunk * 2);
    for (u32 i = threadIdx.x; i < n; i += 64) {
        u64 key = seg[i];
        float s = __uint_as_float((u32)(key >> 32));
        int bin = score_bin(s);
        if ((u32)bin <= B) {
            u32 pos = atomicAdd(&binCur[bin], 1u);
            if (pos < SORTN) sortbuf[pos] = key;
        }
    }
}

// K4: exact rank within bin + decode + scatter; threads beyond M zero-pad
__global__ void __launch_bounds__(256) k_rankpad(
        const float4* __restrict__ loc, const float4* __restrict__ priors,
        const float* __restrict__ landm, const u64* __restrict__ sortbuf,
        const u32* __restrict__ hist, const u32* __restrict__ binStart,
        const u32* __restrict__ ctr,
        float4* __restrict__ selbox, float* __restrict__ selscore,
        float* __restrict__ sellm) {
    u32 M = ctr[2];
    if (M > SORTN) M = SORTN;
    u32 p = blockIdx.x * 256 + threadIdx.x;
    if (p >= M) {
        if (p < TOPK) {
            selbox[p] = make_float4(0.f, 0.f, 0.f, 0.f);
            selscore[p] = 0.f;
            #pragma unroll
            for (int q = 0; q < 10; q++) sellm[(size_t)p * 10 + q] = 0.f;
        }
        return;
    }
    u64 key = sortbuf[p];
    float sc = __uint_as_float((u32)(key >> 32));
    int bin = score_bin(sc);
    u32 st = binStart[bin];
    u32 cnt = hist[bin];
    u32 end = st + cnt;
    if (end > M) end = M;
    u32 rank = st;
    for (u32 j = st; j < end; j++) {
        rank += (sortbuf[j] > key) ? 1u : 0u;
    }
    if (rank >= TOPK) return;
    u32 idx = ~(u32)key;
    float4 L = loc[idx];
    float4 P = priors[idx];
    float cx = P.x + L.x * 0.1f * P.z;
    float cy = P.y + L.y * 0.1f * P.w;
    float wx = P.z * expf(L.z * 0.2f);
    float wy = P.w * expf(L.w * 0.2f);
    float4 bx;
    bx.x = (cx - 0.5f * wx) * 8192.f;
    bx.y = (cy - 0.5f * wy) * 8192.f;
    bx.z = (cx + 0.5f * wx) * 8192.f;
    bx.w = (cy + 0.5f * wy) * 8192.f;
    selbox[rank] = bx;
    selscore[rank] = sc;
    const float* lmr = landm + (size_t)idx * 10;
    float* lmo = sellm + (size_t)rank * 10;
    #pragma unroll
    for (int q = 0; q < 5; q++) {
        float lx = lmr[2 * q], ly = lmr[2 * q + 1];
        lmo[2 * q]     = (P.x + lx * 0.1f * P.z) * 8192.f;
        lmo[2 * q + 1] = (P.y + ly * 0.1f * P.w) * 8192.f;
    }
}

// K5: mask matrix (conflict-free LDS access via lane-consecutive reads + ballots)
// plus per-4-row valid/nonzero bits atomically OR'd into validw/nzw.
__global__ void __launch_bounds__(256) k_mask(const float4* __restrict__ selbox,
                                              const float* __restrict__ selscore,
                                              u64* __restrict__ mask,
                                              u64* __restrict__ validw,
                                              u64* __restrict__ nzw) {
    __shared__ float4 sb[TOPK];   // 64 KB
    int t = threadIdx.x, b = blockIdx.x;
    for (int i = t; i < TOPK; i += 256) sb[i] = selbox[i];
    __syncthreads();
    int wv = t >> 6, lane = t & 63;
    int rbase = b * 16 + wv * 4;
    float4 r0 = sb[rbase], r1 = sb[rbase + 1], r2 = sb[rbase + 2], r3 = sb[rbase + 3];
    float a0 = fmaxf(r0.z - r0.x, 0.f) * fmaxf(r0.w - r0.y, 0.f);
    float a1 = fmaxf(r1.z - r1.x, 0.f) * fmaxf(r1.w - r1.y, 0.f);
    float a2 = fmaxf(r2.z - r2.x, 0.f) * fmaxf(r2.w - r2.y, 0.f);
    float a3 = fmaxf(r3.z - r3.x, 0.f) * fmaxf(r3.w - r3.y, 0.f);
    u64 w0 = 0, w1 = 0, w2 = 0, w3 = 0;
    for (int w = 0; w < 64; w++) {
        if (w * 64 + 63 <= rbase) continue;
        int j = w * 64 + lane;
        float4 bj = sb[j];
        float aj = fmaxf(bj.z - bj.x, 0.f) * fmaxf(bj.w - bj.y, 0.f);
        #define IOU_BIT(rr, aa, row) ({ \
            float lx = fmaxf(rr.x, bj.x), ly = fmaxf(rr.y, bj.y); \
            float rx = fminf(rr.z, bj.z), ry = fminf(rr.w, bj.w); \
            float inter = fmaxf(rx - lx, 0.f) * fmaxf(ry - ly, 0.f); \
            float iou = inter / (aa + aj - inter + 1e-12f); \
            (j > (row)) && (iou > IOU_T); })
        u64 bb0 = __ballot(IOU_BIT(r0, a0, rbase + 0));
        u64 bb1 = __ballot(IOU_BIT(r1, a1, rbase + 1));
        u64 bb2 = __ballot(IOU_BIT(r2, a2, rbase + 2));
        u64 bb3 = __ballot(IOU_BIT(r3, a3, rbase + 3));
        #undef IOU_BIT
        if (lane == w) { w0 = bb0; w1 = bb1; w2 = bb2; w3 = bb3; }
    }
    mask[(size_t)(rbase + 0) * 64 + lane] = w0;
    mask[(size_t)(rbase + 1) * 64 + lane] = w1;
    mask[(size_t)(rbase + 2) * 64 + lane] = w2;
    mask[(size_t)(rbase + 3) * 64 + lane] = w3;
    u64 nz0 = __ballot(w0 != 0ull), nz1 = __ballot(w1 != 0ull);
    u64 nz2 = __ballot(w2 != 0ull), nz3 = __ballot(w3 != 0ull);
    u64 vb = __ballot(lane < 4 && selscore[rbase + lane] > CONF_T);  // bits 0..3
    if (lane == 0) {
        int g = rbase >> 6;
        int sh = rbase & 63;
        u64 nzb = (nz0 ? 1ull : 0) | (nz1 ? 2ull : 0) | (nz2 ? 4ull : 0) | (nz3 ? 8ull : 0);
        if (vb)  atomicOr(&validw[g], vb << sh);
        if (nzb) atomicOr(&nzw[g], nzb << sh);
    }
}

// K6: minimal serial greedy NMS: one wave, registers only; mask gathered on demand
__global__ void k_nms(const u64* __restrict__ mask, const u64* __restrict__ validw_arr,
                      const u64* __restrict__ nzw_arr, u64* __restrict__ keepout) {
    int t = threadIdx.x;  // 64 lanes
    u64 vw = validw_arr[t];
    u64 nzv = nzw_arr[t];
    u64 sup = 0ull, keepw = 0ull;
    for (int g = 0; g < 64; g++) {
        u64 cur = __shfl(sup, g);
        u64 validg = __shfl(vw, g);
        u64 nzg = __shfl(nzv, g);
        u64 alive = (~cur) & validg;
        if (nzg) {
            u64 intra = mask[(size_t)(g * 64 + t) * 64 + g];  // on-demand gather
            u64 rem = nzg;
            while (rem) {
                int bb = __ffsll((long long)rem) - 1;
                rem &= rem - 1;
                if ((alive >> bb) & 1ull) {
                    u64 rowb = __shfl(intra, bb);
                    alive &= ~rowb;
                }
            }
        }
        if (t == g) keepw = alive;
        u64 srem = alive & nzg;
        const u64* mb = mask + (size_t)(g * 64) * 64 + t;
        while (srem) {
            int i0, i1 = -1, i2 = -1, i3 = -1, i4 = -1, i5 = -1, i6 = -1, i7 = -1;
            i0 = __ffsll((long long)srem) - 1; srem &= srem - 1;
            if (srem) { i1 = __ffsll((long long)srem) - 1; srem &= srem - 1;
            if (srem) { i2 = __ffsll((long long)srem) - 1; srem &= srem - 1;
            if (srem) { i3 = __ffsll((long long)srem) - 1; srem &= srem - 1;
            if (srem) { i4 = __ffsll((long long)srem) - 1; srem &= srem - 1;
            if (srem) { i5 = __ffsll((long long)srem) - 1; srem &= srem - 1;
            if (srem) { i6 = __ffsll((long long)srem) - 1; srem &= srem - 1;
            if (srem) { i7 = __ffsll((long long)srem) - 1; srem &= srem - 1; } } } } } } }
            u64 a0 = mb[(size_t)i0 * 64];
            u64 a1 = (i1 >= 0) ? mb[(size_t)i1 * 64] : 0ull;
            u64 a2 = (i2 >= 0) ? mb[(size_t)i2 * 64] : 0ull;
            u64 a3 = (i3 >= 0) ? mb[(size_t)i3 * 64] : 0ull;
            u64 a4 = (i4 >= 0) ? mb[(size_t)i4 * 64] : 0ull;
            u64 a5 = (i5 >= 0) ? mb[(size_t)i5 * 64] : 0ull;
            u64 a6 = (i6 >= 0) ? mb[(size_t)i6 * 64] : 0ull;
            u64 a7 = (i7 >= 0) ? mb[(size_t)i7 * 64] : 0ull;
            sup |= (a0 | a1) | (a2 | a3) | ((a4 | a5) | (a6 | a7));
        }
    }
    keepout[t] = keepw;
}

// K7: massively-parallel output write (one thread per element)
__global__ void __launch_bounds__(256) k_final(
        const float4* __restrict__ selbox, const float* __restrict__ selscore,
        const float* __restrict__ sellm, const u64* __restrict__ keep,
        float* __restrict__ out) {
    int f = blockIdx.x * 256 + threadIdx.x;
    if (f >= TOPK * 15) return;
    int row = f / 15;
    int col = f - row * 15;
    bool kp = (keep[row >> 6] >> (row & 63)) & 1ull;
    const float* sbf = (const float*)selbox;
    float val;
    if (col < 4)       val = sbf[row * 4 + col];
    else if (col == 4) val = selscore[row];
    else               val = sellm[(size_t)row * 10 + (col - 5)];
    out[f] = kp ? val : 0.f;
}

extern "C" void kernel_launch(void* const* d_in, const int* in_sizes, int n_in,
                              void* d_out, int out_size, void* d_ws, size_t ws_size,
                              hipStream_t stream) {
    const float4* loc    = (const float4*)d_in[0];
    const float4* conf4  = (const float4*)d_in[1];
    const float*  landm  = (const float*)d_in[2];
    const float4* priors = (const float4*)d_in[3];
    float* out = (float*)d_out;
    int N = in_sizes[1] / 2;
    int N2 = N / 2;   // float4 elements (2 anchors each)
    const int NBLK = 2048;
    int chunk = (N2 + NBLK - 1) / NBLK;

    char* ws = (char*)d_ws;
    u32* hist     = (u32*)(ws + HIST_OFF);
    u32* ctr      = (u32*)(ws + CTR_OFF);
    u32* binStart = (u32*)(ws + BINSTART_OFF);
    u32* binCur   = (u32*)(ws + BINCUR_OFF);
    u64* validw   = (u64*)(ws + VALIDW_OFF);
    u64* nzw      = (u64*)(ws + NZW_OFF);
    u64* keepp    = (u64*)(ws + KEEP_OFF);
    float4* selbox = (float4*)(ws + SELBOX_OFF);
    float* selsc   = (float*)(ws + SELSC_OFF);
    float* sellm   = (float*)(ws + SELLM_OFF);
    u64* sortbuf  = (u64*)(ws + SORT_OFF);
    u32* cnt      = (u32*)(ws + CNT_OFF);
    u64* maskp    = (u64*)(ws + MASK_OFF);
    u64* cand     = (u64*)(ws + CAND_OFF);

    k_zero<<<16, 256, 0, stream>>>(hist, ctr, validw, nzw);
    k_histcompact<<<NBLK, 256, 0, stream>>>(conf4, N2, chunk, hist, cnt, cand);
    k_scan<<<1, 256, 0, stream>>>(hist, binStart, binCur, ctr);
    k_bucket<<<NBLK, 64, 0, stream>>>(cand, cnt, chunk, ctr, binCur, sortbuf);
    k_rankpad<<<32, 256, 0, stream>>>(loc, priors, landm, sortbuf, hist, binStart, ctr,
                                      selbox, selsc, sellm);
    k_mask<<<256, 256, 0, stream>>>(selbox, selsc, maskp, validw, nzw);
    k_nms<<<1, 64, 0, stream>>>(maskp, validw, nzw, keepp);
    k_final<<<240, 256, 0, stream>>>(selbox, selsc, sellm, keepp, out);
}

// Round 7
// 97.417 us; speedup vs baseline: 4.3241x; 1.2331x over previous
//
#include <hip/hip_runtime.h>
#include <stdint.h>

typedef unsigned long long u64;
typedef unsigned int u32;

#define CONF_T 0.9f
#define IOU_T 0.5f
#define TOPK 4096
#define CAP 384            // per-bin segment capacity (expected ~84, max ~140)

// ---- workspace layout (bytes) ----
#define BINCNT_OFF 0         // u32[4096]       16384
#define VALIDW_OFF 16384     // u64[64]         512
#define NZW_OFF    16896     // u64[64]         512
#define SELBOX_OFF 32768     // float4[4096]    65536
#define SELSC_OFF  98304     // float[4096]     16384
#define SELLM_OFF  114688    // float[40960]    163840
#define MASK_OFF   278528    // u64[4096*64]    2097152
#define BINSEG_OFF 2375680   // u64[4096*384]   12582912

__device__ __forceinline__ int score_bin(float s) {
    u32 b = __float_as_uint(s);
    if (b >= 0x3F800000u) return 0;
    int bin = (int)((0x3F800000u - b) >> 9);
    return bin > 4095 ? 4095 : bin;
}

// K0: zero binCnt + validw/nzw
__global__ void k_zero(u32* __restrict__ binCnt, u64* __restrict__ validw,
                       u64* __restrict__ nzw) {
    int i = blockIdx.x * 256 + threadIdx.x;
    binCnt[i] = 0u;
    if (i < 64) { validw[i] = 0ull; nzw[i] = 0ull; }
}

// K1: single conf scan, candidates scattered directly into per-bin segments.
// binCnt doubles as the histogram.
__global__ void __launch_bounds__(256) k_compact(
        const float4* __restrict__ conf4, int N2,
        u32* __restrict__ binCnt, u64* __restrict__ binseg) {
    int stride = gridDim.x * 256;
    for (int i = blockIdx.x * 256 + threadIdx.x; i < N2; i += stride) {
        float4 v = conf4[i];
        if (v.y > CONF_T) {
            int b = score_bin(v.y);
            u32 p = atomicAdd(&binCnt[b], 1u);
            if (p < CAP)
                binseg[(size_t)b * CAP + p] =
                    ((u64)__float_as_uint(v.y) << 32) | (u64)(~(u32)(2 * i));
        }
        if (v.w > CONF_T) {
            int b = score_bin(v.w);
            u32 p = atomicAdd(&binCnt[b], 1u);
            if (p < CAP)
                binseg[(size_t)b * CAP + p] =
                    ((u64)__float_as_uint(v.w) << 32) | (u64)(~(u32)(2 * i + 1));
        }
    }
}

// K2: per-block redundant prefix scan of binCnt in LDS, then exact rank within
// bin + decode + scatter to rank position; threads beyond M zero-pad.
__global__ void __launch_bounds__(256) k_rankscan(
        const float4* __restrict__ loc, const float4* __restrict__ priors,
        const float* __restrict__ landm, const u32* __restrict__ binCnt,
        const u64* __restrict__ binseg,
        float4* __restrict__ selbox, float* __restrict__ selscore,
        float* __restrict__ sellm) {
    __shared__ u32 pref_s[4097];
    __shared__ u32 parts[256];
    __shared__ u32 m_sh;
    int t = threadIdx.x;
    u32 h[16];
    u32 sum = 0;
    #pragma unroll
    for (int i = 0; i < 16; i++) {
        u32 c = binCnt[t * 16 + i];
        h[i] = c > CAP ? CAP : c;
        sum += h[i];
    }
    parts[t] = sum;
    if (t == 0) m_sh = 0u;
    __syncthreads();
    for (int d = 1; d < 256; d <<= 1) {
        u32 add = (t >= d) ? parts[t - d] : 0u;
        __syncthreads();
        parts[t] += add;
        __syncthreads();
    }
    u32 incl = parts[t];
    u32 excl = incl - sum;
    u32 run = excl;
    #pragma unroll
    for (int i = 0; i < 16; i++) { pref_s[t * 16 + i] = run; run += h[i]; }
    if (t == 255) pref_s[4096] = run;   // total
    __syncthreads();
    u32 total = pref_s[4096];
    u32 target = total < TOPK ? total : TOPK;
    if (total > 0 && excl < target && incl >= target) {
        u32 r2 = excl;
        #pragma unroll
        for (int i = 0; i < 16; i++) {
            r2 += h[i];
            if (r2 >= target) { m_sh = r2; break; }
        }
    }
    __syncthreads();
    u32 M = m_sh;
    u32 p = blockIdx.x * 256 + t;
    if (p >= M) {
        if (p < TOPK) {   // zero-pad unused ranks
            selbox[p] = make_float4(0.f, 0.f, 0.f, 0.f);
            selscore[p] = 0.f;
            #pragma unroll
            for (int q = 0; q < 10; q++) sellm[(size_t)p * 10 + q] = 0.f;
        }
        return;
    }
    // binary search: largest bin with pref_s[bin] <= p
    int lo = 0, hi = 4095;
    while (lo < hi) {
        int mid = (lo + hi + 1) >> 1;
        if (pref_s[mid] <= p) lo = mid; else hi = mid - 1;
    }
    u32 st = pref_s[lo];
    u32 cnt = pref_s[lo + 1] - st;
    const u64* seg = binseg + (size_t)lo * CAP;
    u64 key = seg[p - st];
    u32 rank = st;
    for (u32 j = 0; j < cnt; j++) rank += (seg[j] > key) ? 1u : 0u;
    if (rank >= TOPK) return;
    u32 idx = ~(u32)key;
    float sc = __uint_as_float((u32)(key >> 32));
    float4 L = loc[idx];
    float4 P = priors[idx];
    float cx = P.x + L.x * 0.1f * P.z;
    float cy = P.y + L.y * 0.1f * P.w;
    float wx = P.z * expf(L.z * 0.2f);
    float wy = P.w * expf(L.w * 0.2f);
    float4 bx;
    bx.x = (cx - 0.5f * wx) * 8192.f;
    bx.y = (cy - 0.5f * wy) * 8192.f;
    bx.z = (cx + 0.5f * wx) * 8192.f;
    bx.w = (cy + 0.5f * wy) * 8192.f;
    selbox[rank] = bx;
    selscore[rank] = sc;
    const float* lmr = landm + (size_t)idx * 10;
    float* lmo = sellm + (size_t)rank * 10;
    #pragma unroll
    for (int q = 0; q < 5; q++) {
        float lx = lmr[2 * q], ly = lmr[2 * q + 1];
        lmo[2 * q]     = (P.x + lx * 0.1f * P.z) * 8192.f;
        lmo[2 * q + 1] = (P.y + ly * 0.1f * P.w) * 8192.f;
    }
}

// K3: mask matrix (conflict-free LDS reads + ballots), valid/nonzero bits OR'd
// into validw/nzw, AND unconditional output write for this block's 16 rows.
__global__ void __launch_bounds__(256) k_maskout(
        const float4* __restrict__ selbox, const float* __restrict__ selscore,
        const float* __restrict__ sellm,
        u64* __restrict__ mask, u64* __restrict__ validw, u64* __restrict__ nzw,
        float* __restrict__ out) {
    __shared__ float4 sb[TOPK];   // 64 KB
    int t = threadIdx.x, b = blockIdx.x;
    for (int i = t; i < TOPK; i += 256) sb[i] = selbox[i];
    __syncthreads();
    int wv = t >> 6, lane = t & 63;
    int rbase = b * 16 + wv * 4;
    float4 r0 = sb[rbase], r1 = sb[rbase + 1], r2 = sb[rbase + 2], r3 = sb[rbase + 3];
    float a0 = fmaxf(r0.z - r0.x, 0.f) * fmaxf(r0.w - r0.y, 0.f);
    float a1 = fmaxf(r1.z - r1.x, 0.f) * fmaxf(r1.w - r1.y, 0.f);
    float a2 = fmaxf(r2.z - r2.x, 0.f) * fmaxf(r2.w - r2.y, 0.f);
    float a3 = fmaxf(r3.z - r3.x, 0.f) * fmaxf(r3.w - r3.y, 0.f);
    u64 w0 = 0, w1 = 0, w2 = 0, w3 = 0;
    for (int w = 0; w < 64; w++) {
        if (w * 64 + 63 <= rbase) continue;
        int j = w * 64 + lane;
        float4 bj = sb[j];
        float aj = fmaxf(bj.z - bj.x, 0.f) * fmaxf(bj.w - bj.y, 0.f);
        #define IOU_BIT(rr, aa, row) ({ \
            float lx = fmaxf(rr.x, bj.x), ly = fmaxf(rr.y, bj.y); \
            float rx = fminf(rr.z, bj.z), ry = fminf(rr.w, bj.w); \
            float inter = fmaxf(rx - lx, 0.f) * fmaxf(ry - ly, 0.f); \
            float iou = inter / (aa + aj - inter + 1e-12f); \
            (j > (row)) && (iou > IOU_T); })
        u64 bb0 = __ballot(IOU_BIT(r0, a0, rbase + 0));
        u64 bb1 = __ballot(IOU_BIT(r1, a1, rbase + 1));
        u64 bb2 = __ballot(IOU_BIT(r2, a2, rbase + 2));
        u64 bb3 = __ballot(IOU_BIT(r3, a3, rbase + 3));
        #undef IOU_BIT
        if (lane == w) { w0 = bb0; w1 = bb1; w2 = bb2; w3 = bb3; }
    }
    mask[(size_t)(rbase + 0) * 64 + lane] = w0;
    mask[(size_t)(rbase + 1) * 64 + lane] = w1;
    mask[(size_t)(rbase + 2) * 64 + lane] = w2;
    mask[(size_t)(rbase + 3) * 64 + lane] = w3;
    u64 nz0 = __ballot(w0 != 0ull), nz1 = __ballot(w1 != 0ull);
    u64 nz2 = __ballot(w2 != 0ull), nz3 = __ballot(w3 != 0ull);
    u64 vb = __ballot(lane < 4 && selscore[rbase + lane] > CONF_T);  // bits 0..3
    if (lane == 0) {
        int g = rbase >> 6;
        int sh = rbase & 63;
        u64 nzb = (nz0 ? 1ull : 0) | (nz1 ? 2ull : 0) | (nz2 ? 4ull : 0) | (nz3 ? 8ull : 0);
        if (vb)  atomicOr(&validw[g], vb << sh);
        if (nzb) atomicOr(&nzw[g], nzb << sh);
    }
    // unconditional output write for this block's 16 rows (nms zeroes later)
    if (t < 240) {
        int row = b * 16 + t / 15;
        int col = t - (t / 15) * 15;
        const float* sbf = (const float*)selbox;
        float val;
        if (col < 4)       val = sbf[row * 4 + col];
        else if (col == 4) val = selscore[row];
        else               val = sellm[(size_t)row * 10 + (col - 5)];
        out[(size_t)row * 15 + col] = val;
    }
}

// K4: serial greedy NMS (wave 0) + zeroing of non-kept rows (all 16 waves)
__global__ void __launch_bounds__(1024) k_nmszero(
        const u64* __restrict__ mask, const u64* __restrict__ validw_arr,
        const u64* __restrict__ nzw_arr, float* __restrict__ out) {
    __shared__ u64 keep_s[64];
    int tid = threadIdx.x;
    if (tid < 64) {
        int t = tid;
        u64 vw = validw_arr[t];
        u64 nzv = nzw_arr[t];
        u64 sup = 0ull, keepw = 0ull;
        for (int g = 0; g < 64; g++) {
            u64 cur = __shfl(sup, g);
            u64 validg = __shfl(vw, g);
            u64 nzg = __shfl(nzv, g);
            u64 alive = (~cur) & validg;
            if (nzg) {
                u64 intra = mask[(size_t)(g * 64 + t) * 64 + g];
                u64 rem = nzg;
                while (rem) {
                    int bb = __ffsll((long long)rem) - 1;
                    rem &= rem - 1;
                    if ((alive >> bb) & 1ull) {
                        u64 rowb = __shfl(intra, bb);
                        alive &= ~rowb;
                    }
                }
            }
            if (t == g) keepw = alive;
            u64 srem = alive & nzg;
            const u64* mb = mask + (size_t)(g * 64) * 64 + t;
            while (srem) {
                int i0, i1 = -1, i2 = -1, i3 = -1, i4 = -1, i5 = -1, i6 = -1, i7 = -1;
                i0 = __ffsll((long long)srem) - 1; srem &= srem - 1;
                if (srem) { i1 = __ffsll((long long)srem) - 1; srem &= srem - 1;
                if (srem) { i2 = __ffsll((long long)srem) - 1; srem &= srem - 1;
                if (srem) { i3 = __ffsll((long long)srem) - 1; srem &= srem - 1;
                if (srem) { i4 = __ffsll((long long)srem) - 1; srem &= srem - 1;
                if (srem) { i5 = __ffsll((long long)srem) - 1; srem &= srem - 1;
                if (srem) { i6 = __ffsll((long long)srem) - 1; srem &= srem - 1;
                if (srem) { i7 = __ffsll((long long)srem) - 1; srem &= srem - 1; } } } } } } }
                u64 a0 = mb[(size_t)i0 * 64];
                u64 a1 = (i1 >= 0) ? mb[(size_t)i1 * 64] : 0ull;
                u64 a2 = (i2 >= 0) ? mb[(size_t)i2 * 64] : 0ull;
                u64 a3 = (i3 >= 0) ? mb[(size_t)i3 * 64] : 0ull;
                u64 a4 = (i4 >= 0) ? mb[(size_t)i4 * 64] : 0ull;
                u64 a5 = (i5 >= 0) ? mb[(size_t)i5 * 64] : 0ull;
                u64 a6 = (i6 >= 0) ? mb[(size_t)i6 * 64] : 0ull;
                u64 a7 = (i7 >= 0) ? mb[(size_t)i7 * 64] : 0ull;
                sup |= (a0 | a1) | (a2 | a3) | ((a4 | a5) | (a6 | a7));
            }
        }
        keep_s[t] = keepw;
    }
    __syncthreads();
    for (int r = tid; r < TOPK; r += 1024) {
        if (!((keep_s[r >> 6] >> (r & 63)) & 1ull)) {
            float* o = out + (size_t)r * 15;
            #pragma unroll
            for (int q = 0; q < 15; q++) o[q] = 0.f;
        }
    }
}

extern "C" void kernel_launch(void* const* d_in, const int* in_sizes, int n_in,
                              void* d_out, int out_size, void* d_ws, size_t ws_size,
                              hipStream_t stream) {
    const float4* loc    = (const float4*)d_in[0];
    const float4* conf4  = (const float4*)d_in[1];
    const float*  landm  = (const float*)d_in[2];
    const float4* priors = (const float4*)d_in[3];
    float* out = (float*)d_out;
    int N = in_sizes[1] / 2;
    int N2 = N / 2;   // float4 elements (2 anchors each)

    char* ws = (char*)d_ws;
    u32* binCnt   = (u32*)(ws + BINCNT_OFF);
    u64* validw   = (u64*)(ws + VALIDW_OFF);
    u64* nzw      = (u64*)(ws + NZW_OFF);
    float4* selbox = (float4*)(ws + SELBOX_OFF);
    float* selsc   = (float*)(ws + SELSC_OFF);
    float* sellm   = (float*)(ws + SELLM_OFF);
    u64* maskp    = (u64*)(ws + MASK_OFF);
    u64* binseg   = (u64*)(ws + BINSEG_OFF);

    k_zero<<<16, 256, 0, stream>>>(binCnt, validw, nzw);
    k_compact<<<1024, 256, 0, stream>>>(conf4, N2, binCnt, binseg);
    k_rankscan<<<32, 256, 0, stream>>>(loc, priors, landm, binCnt, binseg,
                                       selbox, selsc, sellm);
    k_maskout<<<256, 256, 0, stream>>>(selbox, selsc, sellm, maskp, validw, nzw, out);
    k_nmszero<<<1, 1024, 0, stream>>>(maskp, validw, nzw, out);
}